// Round 10
// baseline (36.109 us; speedup 1.0000x reference)
//
#include <hip/hip_runtime.h>
#include <math.h>

// Problem constants (match reference)
#define BATCH 4
#define LSEQ  4096
#define DCH   512
#define NST   16
#define DBLK  4                    // d-channels per block
#define TCH   32                   // chunk length along L
#define CCH   (LSEQ / TCH)         // 128 chunks
#define TPB   (DBLK * CCH)         // 512 threads per block
#define NCHAIN (DBLK * NST)        // 64 (d,n) chains per block
#define SSTR  (CCH + 1)            // 129: mod 32 == 1 -> P2 lane accesses 2-way free
#define SEG   16                   // chunks per P2 segment
#define NSEG  (CCH / SEG)          // 8 segments

// One block = (batch b, 4-channel slice), full L in-block, one launch.
// g-space recurrence: g = g*dA + x;  y = dot(g, dB).
//   P1: local g-scan of one 32-step chunk -> chunk-exit g into LDS
//   P2: two-level work-efficient scan over 128 chunks (3 barriers total):
//       P2a: thread register-scans a 16-chunk segment of one chain
//       P2b: carry-in from <=7 segment totals (weighted by (dA^32)^16 powers)
//       P2c: apply carry with powers of dA^32, write back
//   P3: entry = scanned[c-1]; replay chunk (x re-read, L2/L3-hot); y out
__global__ __launch_bounds__(TPB) void mamba_one(
    const float* __restrict__ x, const float* __restrict__ A,
    const float* __restrict__ Bm, const float* __restrict__ delta,
    float* __restrict__ y)
{
    __shared__ float v[NCHAIN * SSTR];     // 64 x 129 x 4B = 33 KB
    __shared__ float aT[NCHAIN];           // dA^TCH per chain
    __shared__ float tot[NSEG * NCHAIN];   // 8 x 64 x 4B = 2 KB

    // XCD swizzle: consecutive logical blocks (adjacent d-groups, shared
    // x cache lines) land on the same XCD's L2. grid=512 -> 64 per XCD.
    const int lb   = (blockIdx.x & 7) * 64 + (blockIdx.x >> 3);  // 0..511
    const int b    = lb >> 7;                // 0..3
    const int dgrp = lb & 127;               // 0..127
    const int d0   = dgrp * DBLK;

    const int tid = threadIdx.x;
    const int d   = tid & (DBLK - 1);        // 0..3
    const int c   = tid >> 2;                // 0..127

    const int dg   = d0 + d;                 // global channel
    const float dl = delta[dg];

    float dA[NST], g[NST];
    const float4* Arow = (const float4*)(A + dg * NST);
#pragma unroll
    for (int q = 0; q < 4; ++q) {
        float4 a4 = Arow[q];
        dA[4*q+0] = expf(dl * a4.x);
        dA[4*q+1] = expf(dl * a4.y);
        dA[4*q+2] = expf(dl * a4.z);
        dA[4*q+3] = expf(dl * a4.w);
    }
#pragma unroll
    for (int n = 0; n < NST; ++n) g[n] = 0.f;

    // chain decay table: thread (d, c=n<16) publishes dA[n]^32 for chain n*4+d
    if (c < NST) {
        float p = dA[c];
#pragma unroll
        for (int k = 0; k < 5; ++k) p *= p;   // ^32
        aT[c * DBLK + d] = p;
    }

    // ---- Phase 1: local g-scan of chunk c (g0 = 0); exit g -> LDS ----
    const float* xp = x + ((size_t)b * LSEQ + (size_t)c * TCH) * DCH + dg;
#pragma unroll
    for (int t = 0; t < TCH; ++t) {
        float xv = xp[(size_t)t * DCH];
#pragma unroll
        for (int n = 0; n < NST; ++n)
            g[n] = fmaf(g[n], dA[n], xv);
    }
#pragma unroll
    for (int n = 0; n < NST; ++n)
        v[(n * DBLK + d) * SSTR + c] = g[n];

    __syncthreads();

    // ---- Phase 2: two-level scan along c (64 chains x 128 chunks) ----
    {
        const int ch = tid & (NCHAIN - 1);   // chain: wave = 64 distinct chains
        const int s  = tid >> 6;             // segment 0..7
        const float aTc = aT[ch];
        float aT16 = aTc;
#pragma unroll
        for (int k = 0; k < 4; ++k) aT16 *= aT16;   // (dA^32)^16

        // P2a: register inclusive scan of this segment
        float sv[SEG];
#pragma unroll
        for (int i = 0; i < SEG; ++i)
            sv[i] = v[ch * SSTR + s * SEG + i];
#pragma unroll
        for (int i = 1; i < SEG; ++i)
            sv[i] = fmaf(sv[i-1], aTc, sv[i]);

        tot[s * NCHAIN + ch] = sv[SEG - 1];
        __syncthreads();

        // P2b: carry-in = scan of previous segment totals (decay aT16)
        float pfx = 0.f;
#pragma unroll
        for (int j = 0; j < NSEG - 1; ++j) {
            float Tj = tot[j * NCHAIN + ch];
            float np = fmaf(pfx, aT16, Tj);
            pfx = (j < s) ? np : pfx;
        }

        // P2c: apply carry with powers of aTc, write back
        float w = aTc;
#pragma unroll
        for (int i = 0; i < SEG; ++i) {
            v[ch * SSTR + s * SEG + i] = fmaf(pfx, w, sv[i]);
            w *= aTc;
        }
        __syncthreads();
    }

    // ---- Phase 3: entry = scanned[c-1]; replay chunk; y = dot(g,dB) ----
#pragma unroll
    for (int n = 0; n < NST; ++n) {
        int cm = (c > 0) ? (c - 1) : 0;
        float e = v[(n * DBLK + d) * SSTR + cm];
        g[n] = (c > 0) ? e : 0.f;
    }

    float dB[NST];
    const float4* Brow = (const float4*)(Bm + dg * NST);
#pragma unroll
    for (int q = 0; q < 4; ++q) {
        float4 b4 = Brow[q];
        dB[4*q+0] = dl * b4.x;
        dB[4*q+1] = dl * b4.y;
        dB[4*q+2] = dl * b4.z;
        dB[4*q+3] = dl * b4.w;
    }

    float* yp = y + ((size_t)b * LSEQ + (size_t)c * TCH) * DCH + dg;
#pragma unroll
    for (int t = 0; t < TCH; ++t) {
        float xv = xp[(size_t)t * DCH];
#pragma unroll
        for (int n = 0; n < NST; ++n)
            g[n] = fmaf(g[n], dA[n], xv);
        float a0 = 0.f, a1 = 0.f, a2 = 0.f, a3 = 0.f;
#pragma unroll
        for (int n = 0; n < NST; n += 4) {
            a0 = fmaf(g[n+0], dB[n+0], a0);
            a1 = fmaf(g[n+1], dB[n+1], a1);
            a2 = fmaf(g[n+2], dB[n+2], a2);
            a3 = fmaf(g[n+3], dB[n+3], a3);
        }
        yp[(size_t)t * DCH] = (a0 + a1) + (a2 + a3);
    }
}

extern "C" void kernel_launch(void* const* d_in, const int* in_sizes, int n_in,
                              void* d_out, int out_size, void* d_ws, size_t ws_size,
                              hipStream_t stream) {
    const float* x     = (const float*)d_in[0];   // (B, L, D)
    const float* A     = (const float*)d_in[1];   // (D, N)
    const float* Bm    = (const float*)d_in[2];   // (D, N)
    const float* delta = (const float*)d_in[3];   // (D,)
    float*       y     = (float*)d_out;           // (B, L, D)

    const int nblocks = BATCH * (DCH / DBLK);     // 512 blocks, 2 per CU
    mamba_one<<<nblocks, TPB, 0, stream>>>(x, A, Bm, delta, y);
}

// Round 11
// 28.872 us; speedup vs baseline: 1.2506x; 1.2506x over previous
//
#include <hip/hip_runtime.h>
#include <math.h>

// Problem constants (match reference)
#define BATCH 4
#define LSEQ  4096
#define DCH   512
#define NST   16
#define DBLK  8                    // d-channels per block
#define TCH   32                   // chunk length along L
#define CCH   (LSEQ / TCH)         // 128 chunks
#define TPB   (DBLK * CCH)         // 1024 threads per block
#define NCHAIN (DBLK * NST)        // 128 (d,n) chains per block
#define CSTR  (NCHAIN + 4)         // 132: bank spread 4/c -> every access <=2-way
#define SEG   16                   // chunks per P2 segment
#define NSEG  (CCH / SEG)          // 8 segments

// One block = (batch b, 8-channel slice), full L in-block, one launch.
// g-space recurrence: g = g*dA + x;  y = dot(g, dB).
// LDS v layout: v[chunk][chain], chain = n*DBLK + d, stride CSTR=132.
//   P1: local g-scan of one 32-step chunk -> chunk-exit g into v
//   P2: work-efficient scan over 128 chunks (3 barriers):
//       P2a thread register-scans 16 chunks of one chain; totals -> tot
//       P2b carry-in from <=7 segment totals (decay (dA^32)^16)
//       P2c apply carry with powers of dA^32, write back inclusive values
//   P3: entry = v[c-1]; replay chunk (x re-read, cache-hot); y = dot(g,dB)
__global__ __launch_bounds__(TPB) void mamba_one(
    const float* __restrict__ x, const float* __restrict__ A,
    const float* __restrict__ Bm, const float* __restrict__ delta,
    float* __restrict__ y)
{
    __shared__ float v[CCH * CSTR];      // 128 x 132 x 4B = 67.6 KB
    __shared__ float aT[NCHAIN];         // dA^TCH per chain
    __shared__ float tot[NSEG * NCHAIN]; // 8 x 128 x 4B = 4 KB

    // XCD swizzle: consecutive logical blocks (adjacent d-groups, shared
    // x cache lines) land on the same XCD's L2. 256 = 8 XCD x 32.
    const int lb   = (blockIdx.x & 7) * 32 + (blockIdx.x >> 3);  // 0..255
    const int b    = lb >> 6;                // 0..3
    const int dgrp = lb & 63;                // 0..63
    const int d0   = dgrp * DBLK;

    const int tid = threadIdx.x;
    const int d   = tid & (DBLK - 1);        // 0..7
    const int c   = tid >> 3;                // 0..127

    const int dg   = d0 + d;                 // global channel
    const float dl = delta[dg];

    float dA[NST], g[NST];
    const float4* Arow = (const float4*)(A + dg * NST);
#pragma unroll
    for (int q = 0; q < 4; ++q) {
        float4 a4 = Arow[q];
        dA[4*q+0] = expf(dl * a4.x);
        dA[4*q+1] = expf(dl * a4.y);
        dA[4*q+2] = expf(dl * a4.z);
        dA[4*q+3] = expf(dl * a4.w);
    }
#pragma unroll
    for (int n = 0; n < NST; ++n) g[n] = 0.f;

    // chain decay table: thread (d, c=n<16) publishes dA[n]^32 for chain n*8+d
    if (c < NST) {
        float p = dA[c];
#pragma unroll
        for (int k = 0; k < 5; ++k) p *= p;   // ^32
        aT[c * DBLK + d] = p;
    }

    // ---- Phase 1: local g-scan of chunk c (g0 = 0); exit g -> v ----
    const float* xp = x + ((size_t)b * LSEQ + (size_t)c * TCH) * DCH + dg;
#pragma unroll
    for (int t = 0; t < TCH; ++t) {
        float xv = xp[(size_t)t * DCH];
#pragma unroll
        for (int n = 0; n < NST; ++n)
            g[n] = fmaf(g[n], dA[n], xv);
    }
#pragma unroll
    for (int n = 0; n < NST; ++n)
        v[c * CSTR + (n * DBLK + d)] = g[n];

    __syncthreads();

    // ---- Phase 2: work-efficient scan along c (128 chains x 128 chunks) ----
    {
        const int ch = tid & (NCHAIN - 1);   // chain (lane-consecutive)
        const int s  = tid >> 7;             // segment 0..7
        const float aTc = aT[ch];
        float aT16 = aTc;
#pragma unroll
        for (int k = 0; k < 4; ++k) aT16 *= aT16;   // (dA^32)^16

        // P2a: register inclusive scan of this 16-chunk segment
        float sv[SEG];
#pragma unroll
        for (int i = 0; i < SEG; ++i)
            sv[i] = v[(s * SEG + i) * CSTR + ch];
#pragma unroll
        for (int i = 1; i < SEG; ++i)
            sv[i] = fmaf(sv[i-1], aTc, sv[i]);

        tot[s * NCHAIN + ch] = sv[SEG - 1];
        __syncthreads();

        // P2b: carry-in = decayed scan of previous segment totals
        float pfx = 0.f;
#pragma unroll
        for (int j = 0; j < NSEG - 1; ++j) {
            float Tj = tot[j * NCHAIN + ch];
            float np = fmaf(pfx, aT16, Tj);
            pfx = (j < s) ? np : pfx;
        }

        // P2c: apply carry with powers of aTc, write back inclusive values
        float w = aTc;
#pragma unroll
        for (int i = 0; i < SEG; ++i) {
            v[(s * SEG + i) * CSTR + ch] = fmaf(pfx, w, sv[i]);
            w *= aTc;
        }
        __syncthreads();
    }

    // ---- Phase 3: entry = v[c-1]; replay chunk; y = dot(g, dB) ----
#pragma unroll
    for (int n = 0; n < NST; ++n) {
        int cm = (c > 0) ? (c - 1) : 0;
        float e = v[cm * CSTR + (n * DBLK + d)];
        g[n] = (c > 0) ? e : 0.f;
    }

    float dB[NST];
    const float4* Brow = (const float4*)(Bm + dg * NST);
#pragma unroll
    for (int q = 0; q < 4; ++q) {
        float4 b4 = Brow[q];
        dB[4*q+0] = dl * b4.x;
        dB[4*q+1] = dl * b4.y;
        dB[4*q+2] = dl * b4.z;
        dB[4*q+3] = dl * b4.w;
    }

    float* yp = y + ((size_t)b * LSEQ + (size_t)c * TCH) * DCH + dg;
#pragma unroll
    for (int t = 0; t < TCH; ++t) {
        float xv = xp[(size_t)t * DCH];
#pragma unroll
        for (int n = 0; n < NST; ++n)
            g[n] = fmaf(g[n], dA[n], xv);
        float a0 = 0.f, a1 = 0.f, a2 = 0.f, a3 = 0.f;
#pragma unroll
        for (int n = 0; n < NST; n += 4) {
            a0 = fmaf(g[n+0], dB[n+0], a0);
            a1 = fmaf(g[n+1], dB[n+1], a1);
            a2 = fmaf(g[n+2], dB[n+2], a2);
            a3 = fmaf(g[n+3], dB[n+3], a3);
        }
        yp[(size_t)t * DCH] = (a0 + a1) + (a2 + a3);
    }
}

extern "C" void kernel_launch(void* const* d_in, const int* in_sizes, int n_in,
                              void* d_out, int out_size, void* d_ws, size_t ws_size,
                              hipStream_t stream) {
    const float* x     = (const float*)d_in[0];   // (B, L, D)
    const float* A     = (const float*)d_in[1];   // (D, N)
    const float* Bm    = (const float*)d_in[2];   // (D, N)
    const float* delta = (const float*)d_in[3];   // (D,)
    float*       y     = (float*)d_out;           // (B, L, D)

    const int nblocks = BATCH * (DCH / DBLK);     // 256 blocks, 1 per CU
    mamba_one<<<nblocks, TPB, 0, stream>>>(x, A, Bm, delta, y);
}

// Round 12
// 26.775 us; speedup vs baseline: 1.3486x; 1.0783x over previous
//
#include <hip/hip_runtime.h>
#include <math.h>

// Problem constants (match reference)
#define BATCH 4
#define LSEQ  4096
#define DCH   512
#define NST   16
#define DBLK  8                    // d-channels per block
#define TCH   32                   // chunk length along L
#define CCH   (LSEQ / TCH)         // 128 chunks
#define TPB   (DBLK * CCH)         // 1024 threads per block
#define NCHAIN (DBLK * NST)        // 128 (d,n) chains per block
#define CSTR  (NCHAIN + 4)         // 132: bank spread 4/chunk -> all accesses <=2-way
#define SEG   16                   // chunks per P2 segment
#define NSEG  (CCH / SEG)          // 8 segments

// One block = (batch b, 8-channel slice), full L in-block, one launch.
// g-space recurrence: g = g*dA + x;  y = dot(g, dB).
// LDS v layout: v[chunk][chain], chain = n*DBLK + d, stride CSTR=132.
//   P1: local g-scan of one 32-step chunk -> chunk-exit g into v
//   PF: prefetch P3's x chunk into registers + dB (latency hidden under P2)
//   P2: work-efficient scan over 128 chunks (3 barriers)
//   P3: entry = v[c-1]; replay chunk from registers; y = dot(g, dB)
__global__ __launch_bounds__(TPB) void mamba_one(
    const float* __restrict__ x, const float* __restrict__ A,
    const float* __restrict__ Bm, const float* __restrict__ delta,
    float* __restrict__ y)
{
    __shared__ float v[CCH * CSTR];      // 128 x 132 x 4B = 67.6 KB
    __shared__ float aT[NCHAIN];         // dA^TCH per chain
    __shared__ float tot[NSEG * NCHAIN]; // 8 x 128 x 4B = 4 KB

    // XCD swizzle: consecutive logical blocks (adjacent d-groups, shared
    // x cache lines) land on the same XCD's L2. 256 = 8 XCD x 32.
    const int lb   = (blockIdx.x & 7) * 32 + (blockIdx.x >> 3);  // 0..255
    const int b    = lb >> 6;                // 0..3
    const int dgrp = lb & 63;                // 0..63
    const int d0   = dgrp * DBLK;

    const int tid = threadIdx.x;
    const int d   = tid & (DBLK - 1);        // 0..7
    const int c   = tid >> 3;                // 0..127

    const int dg   = d0 + d;                 // global channel
    const float dl = delta[dg];

    float dA[NST], g[NST];
    const float4* Arow = (const float4*)(A + dg * NST);
#pragma unroll
    for (int q = 0; q < 4; ++q) {
        float4 a4 = Arow[q];
        dA[4*q+0] = expf(dl * a4.x);
        dA[4*q+1] = expf(dl * a4.y);
        dA[4*q+2] = expf(dl * a4.z);
        dA[4*q+3] = expf(dl * a4.w);
    }
#pragma unroll
    for (int n = 0; n < NST; ++n) g[n] = 0.f;

    // chain decay table: thread (d, c=n<16) publishes dA[n]^32 for chain n*8+d
    if (c < NST) {
        float p = dA[c];
#pragma unroll
        for (int k = 0; k < 5; ++k) p *= p;   // ^32
        aT[c * DBLK + d] = p;
    }

    // ---- Phase 1: local g-scan of chunk c (g0 = 0); exit g -> v ----
    const float* xp = x + ((size_t)b * LSEQ + (size_t)c * TCH) * DCH + dg;
#pragma unroll
    for (int t = 0; t < TCH; ++t) {
        float xv1 = xp[(size_t)t * DCH];
#pragma unroll
        for (int n = 0; n < NST; ++n)
            g[n] = fmaf(g[n], dA[n], xv1);
    }
#pragma unroll
    for (int n = 0; n < NST; ++n)
        v[c * CSTR + (n * DBLK + d)] = g[n];

    // ---- PF: prefetch P3's x into registers + dB; latency hides under P2 ----
    float xv[TCH];
#pragma unroll
    for (int t = 0; t < TCH; ++t)
        xv[t] = xp[(size_t)t * DCH];

    float dB[NST];
    const float4* Brow = (const float4*)(Bm + dg * NST);
#pragma unroll
    for (int q = 0; q < 4; ++q) {
        float4 b4 = Brow[q];
        dB[4*q+0] = dl * b4.x;
        dB[4*q+1] = dl * b4.y;
        dB[4*q+2] = dl * b4.z;
        dB[4*q+3] = dl * b4.w;
    }

    __syncthreads();

    // ---- Phase 2: work-efficient scan along c (128 chains x 128 chunks) ----
    {
        const int ch = tid & (NCHAIN - 1);   // chain (lane-consecutive)
        const int s  = tid >> 7;             // segment 0..7
        const float aTc = aT[ch];
        float aT16 = aTc;
#pragma unroll
        for (int k = 0; k < 4; ++k) aT16 *= aT16;   // (dA^32)^16

        // P2a: register inclusive scan of this 16-chunk segment
        float sv[SEG];
#pragma unroll
        for (int i = 0; i < SEG; ++i)
            sv[i] = v[(s * SEG + i) * CSTR + ch];
#pragma unroll
        for (int i = 1; i < SEG; ++i)
            sv[i] = fmaf(sv[i-1], aTc, sv[i]);

        tot[s * NCHAIN + ch] = sv[SEG - 1];
        __syncthreads();

        // P2b: carry-in = decayed scan of previous segment totals
        float pfx = 0.f;
#pragma unroll
        for (int j = 0; j < NSEG - 1; ++j) {
            float Tj = tot[j * NCHAIN + ch];
            float np = fmaf(pfx, aT16, Tj);
            pfx = (j < s) ? np : pfx;
        }

        // P2c: apply carry with powers of aTc, write back inclusive values
        float w = aTc;
#pragma unroll
        for (int i = 0; i < SEG; ++i) {
            v[(s * SEG + i) * CSTR + ch] = fmaf(pfx, w, sv[i]);
            w *= aTc;
        }
        __syncthreads();
    }

    // ---- Phase 3: entry = v[c-1]; replay from registers; y = dot(g, dB) ----
#pragma unroll
    for (int n = 0; n < NST; ++n) {
        int cm = (c > 0) ? (c - 1) : 0;
        float e = v[cm * CSTR + (n * DBLK + d)];
        g[n] = (c > 0) ? e : 0.f;
    }

    float* yp = y + ((size_t)b * LSEQ + (size_t)c * TCH) * DCH + dg;
#pragma unroll
    for (int t = 0; t < TCH; ++t) {
#pragma unroll
        for (int n = 0; n < NST; ++n)
            g[n] = fmaf(g[n], dA[n], xv[t]);
        float a0 = 0.f, a1 = 0.f, a2 = 0.f, a3 = 0.f;
#pragma unroll
        for (int n = 0; n < NST; n += 4) {
            a0 = fmaf(g[n+0], dB[n+0], a0);
            a1 = fmaf(g[n+1], dB[n+1], a1);
            a2 = fmaf(g[n+2], dB[n+2], a2);
            a3 = fmaf(g[n+3], dB[n+3], a3);
        }
        yp[(size_t)t * DCH] = (a0 + a1) + (a2 + a3);
    }
}

extern "C" void kernel_launch(void* const* d_in, const int* in_sizes, int n_in,
                              void* d_out, int out_size, void* d_ws, size_t ws_size,
                              hipStream_t stream) {
    const float* x     = (const float*)d_in[0];   // (B, L, D)
    const float* A     = (const float*)d_in[1];   // (D, N)
    const float* Bm    = (const float*)d_in[2];   // (D, N)
    const float* delta = (const float*)d_in[3];   // (D,)
    float*       y     = (float*)d_out;           // (B, L, D)

    const int nblocks = BATCH * (DCH / DBLK);     // 256 blocks, 1 per CU
    mamba_one<<<nblocks, TPB, 0, stream>>>(x, A, Bm, delta, y);
}

// Round 13
// 24.468 us; speedup vs baseline: 1.4757x; 1.0943x over previous
//
#include <hip/hip_runtime.h>
#include <math.h>

// Problem constants (match reference)
#define BATCH 4
#define LSEQ  4096
#define DCH   512
#define NST   16
#define DBLK  8                    // d-channels per block
#define TCH   32                   // chunk length along L
#define CCH   (LSEQ / TCH)         // 128 chunks
#define TPB   (DBLK * CCH)         // 1024 threads per block
#define NCHAIN (DBLK * NST)        // 128 (d,n) chains per block
#define CSTR  (NCHAIN + 4)         // 132: bank spread 4/chunk -> all accesses <=2-way
#define SEG   16                   // chunks per P2 segment
#define NSEG  (CCH / SEG)          // 8 segments

// One block = (batch b, 8-channel slice), full L in-block, one launch.
// g-space recurrence: g = g*dA + x;  y = dot(g, dB).
// LDS v layout: v[chunk][chain], chain = n*DBLK + d, stride CSTR=132.
//   P1: issue all 32 x loads -> xv[] (32 in flight); local g-scan; exit g -> v
//       then PIN xv[] with opaque asm so it stays in VGPRs across P2
//       (compiler otherwise sinks/remat's the loads into P3 - R12 evidence)
//   P2: work-efficient scan over 128 chunks (3 barriers)
//   P3: entry = v[c-1]; replay entirely from registers; y = dot(g, dB)
__global__ __launch_bounds__(TPB) void mamba_one(
    const float* __restrict__ x, const float* __restrict__ A,
    const float* __restrict__ Bm, const float* __restrict__ delta,
    float* __restrict__ y)
{
    __shared__ float v[CCH * CSTR];      // 128 x 132 x 4B = 67.6 KB
    __shared__ float aT[NCHAIN];         // dA^TCH per chain
    __shared__ float tot[NSEG * NCHAIN]; // 8 x 128 x 4B = 4 KB

    // XCD swizzle: consecutive logical blocks (adjacent d-groups, shared
    // x cache lines) land on the same XCD's L2. 256 = 8 XCD x 32.
    const int lb   = (blockIdx.x & 7) * 32 + (blockIdx.x >> 3);  // 0..255
    const int b    = lb >> 6;                // 0..3
    const int dgrp = lb & 63;                // 0..63
    const int d0   = dgrp * DBLK;

    const int tid = threadIdx.x;
    const int d   = tid & (DBLK - 1);        // 0..7
    const int c   = tid >> 3;                // 0..127

    const int dg   = d0 + d;                 // global channel
    const float dl = delta[dg];

    float dA[NST], g[NST];
    const float4* Arow = (const float4*)(A + dg * NST);
#pragma unroll
    for (int q = 0; q < 4; ++q) {
        float4 a4 = Arow[q];
        dA[4*q+0] = expf(dl * a4.x);
        dA[4*q+1] = expf(dl * a4.y);
        dA[4*q+2] = expf(dl * a4.z);
        dA[4*q+3] = expf(dl * a4.w);
    }
#pragma unroll
    for (int n = 0; n < NST; ++n) g[n] = 0.f;

    // chain decay table: thread (d, c=n<16) publishes dA[n]^32 for chain n*8+d
    if (c < NST) {
        float p = dA[c];
#pragma unroll
        for (int k = 0; k < 5; ++k) p *= p;   // ^32
        aT[c * DBLK + d] = p;
    }

    // ---- Phase 1: issue ALL x loads, then g-scan; exit g -> v ----
    const float* xp = x + ((size_t)b * LSEQ + (size_t)c * TCH) * DCH + dg;
    float xv[TCH];
#pragma unroll
    for (int t = 0; t < TCH; ++t)
        xv[t] = xp[(size_t)t * DCH];      // 32 independent loads in flight

#pragma unroll
    for (int t = 0; t < TCH; ++t) {
#pragma unroll
        for (int n = 0; n < NST; ++n)
            g[n] = fmaf(g[n], dA[n], xv[t]);
    }
#pragma unroll
    for (int n = 0; n < NST; ++n)
        v[c * CSTR + (n * DBLK + d)] = g[n];

    // Pin xv in registers NOW (before the barrier): opaque def prevents the
    // compiler from rematerializing the loads after P2.
#pragma unroll
    for (int t = 0; t < TCH; ++t)
        asm volatile("" : "+v"(xv[t]));

    __syncthreads();

    // ---- Phase 2: work-efficient scan along c (128 chains x 128 chunks) ----
    {
        const int ch = tid & (NCHAIN - 1);   // chain (lane-consecutive)
        const int s  = tid >> 7;             // segment 0..7
        const float aTc = aT[ch];
        float aT16 = aTc;
#pragma unroll
        for (int k = 0; k < 4; ++k) aT16 *= aT16;   // (dA^32)^16

        // P2a: register inclusive scan of this 16-chunk segment
        float sv[SEG];
#pragma unroll
        for (int i = 0; i < SEG; ++i)
            sv[i] = v[(s * SEG + i) * CSTR + ch];
#pragma unroll
        for (int i = 1; i < SEG; ++i)
            sv[i] = fmaf(sv[i-1], aTc, sv[i]);

        tot[s * NCHAIN + ch] = sv[SEG - 1];
        __syncthreads();

        // P2b: carry-in = decayed scan of previous segment totals
        float pfx = 0.f;
#pragma unroll
        for (int j = 0; j < NSEG - 1; ++j) {
            float Tj = tot[j * NCHAIN + ch];
            float np = fmaf(pfx, aT16, Tj);
            pfx = (j < s) ? np : pfx;
        }

        // P2c: apply carry with powers of aTc, write back inclusive values
        float w = aTc;
#pragma unroll
        for (int i = 0; i < SEG; ++i) {
            v[(s * SEG + i) * CSTR + ch] = fmaf(pfx, w, sv[i]);
            w *= aTc;
        }
        __syncthreads();
    }

    // ---- Phase 3: entry = v[c-1]; replay from registers; y = dot(g, dB) ----
#pragma unroll
    for (int n = 0; n < NST; ++n) {
        int cm = (c > 0) ? (c - 1) : 0;
        float e = v[cm * CSTR + (n * DBLK + d)];
        g[n] = (c > 0) ? e : 0.f;
    }

    float dB[NST];
    const float4* Brow = (const float4*)(Bm + dg * NST);
#pragma unroll
    for (int q = 0; q < 4; ++q) {
        float4 b4 = Brow[q];
        dB[4*q+0] = dl * b4.x;
        dB[4*q+1] = dl * b4.y;
        dB[4*q+2] = dl * b4.z;
        dB[4*q+3] = dl * b4.w;
    }

    float* yp = y + ((size_t)b * LSEQ + (size_t)c * TCH) * DCH + dg;
#pragma unroll
    for (int t = 0; t < TCH; ++t) {
#pragma unroll
        for (int n = 0; n < NST; ++n)
            g[n] = fmaf(g[n], dA[n], xv[t]);
        float a0 = 0.f, a1 = 0.f, a2 = 0.f, a3 = 0.f;
#pragma unroll
        for (int n = 0; n < NST; n += 4) {
            a0 = fmaf(g[n+0], dB[n+0], a0);
            a1 = fmaf(g[n+1], dB[n+1], a1);
            a2 = fmaf(g[n+2], dB[n+2], a2);
            a3 = fmaf(g[n+3], dB[n+3], a3);
        }
        yp[(size_t)t * DCH] = (a0 + a1) + (a2 + a3);
    }
}

extern "C" void kernel_launch(void* const* d_in, const int* in_sizes, int n_in,
                              void* d_out, int out_size, void* d_ws, size_t ws_size,
                              hipStream_t stream) {
    const float* x     = (const float*)d_in[0];   // (B, L, D)
    const float* A     = (const float*)d_in[1];   // (D, N)
    const float* Bm    = (const float*)d_in[2];   // (D, N)
    const float* delta = (const float*)d_in[3];   // (D,)
    float*       y     = (float*)d_out;           // (B, L, D)

    const int nblocks = BATCH * (DCH / DBLK);     // 256 blocks, 1 per CU
    mamba_one<<<nblocks, TPB, 0, stream>>>(x, A, Bm, delta, y);
}